// Round 1
// baseline (5092.724 us; speedup 1.0000x reference)
//
#include <hip/hip_runtime.h>
#include <hip/hip_bf16.h>

#define IN_DIM 128
#define HID 256
#define BN_EPS 1e-5f

// ---------- dtype helpers ----------
__device__ __forceinline__ float ld_f(const void* p, size_t i, int bf16) {
  if (bf16) return __bfloat162float(((const __hip_bfloat16*)p)[i]);
  return ((const float*)p)[i];
}

// flags[0] = 1 if float arrays are bf16, 0 if f32
// flags[1] = 1 if edge_index is int32, 0 if int64
__global__ void detect_kernel(const unsigned int* __restrict__ xw,
                              const unsigned int* __restrict__ eiw,
                              int* flags) {
  if (blockIdx.x == 0 && threadIdx.x == 0) {
    int votes = 0;
    for (int i = 0; i < 256; ++i) {
      unsigned int e = (xw[i] >> 7) & 0xFFu;  // bf16 exponent field if packed bf16
      if (e >= 100u && e <= 140u) ++votes;
    }
    flags[0] = (votes > 128) ? 1 : 0;
    int nz = 0;
    for (int i = 0; i < 256; ++i)
      if (eiw[2 * i + 1] != 0u) ++nz;  // int64 node ids < 50000 -> high words all 0
    flags[1] = (nz > 0) ? 1 : 0;
  }
}

__global__ void convert_idx_kernel(const void* __restrict__ ei, const int* __restrict__ flags,
                                   int* __restrict__ src, int* __restrict__ dst, int n_edges) {
  int i = blockIdx.x * blockDim.x + threadIdx.x;
  int total = 2 * n_edges;
  if (i >= total) return;
  int v;
  if (flags[1]) v = ((const int*)ei)[i];
  else          v = (int)((const long long*)ei)[i];
  if (i < n_edges) src[i] = v;
  else             dst[i - n_edges] = v;
}

__global__ void convert_x_kernel(const void* __restrict__ x, const int* __restrict__ flags,
                                 float* __restrict__ x32, size_t n) {
  int bf = flags[0];
  size_t i = (size_t)blockIdx.x * blockDim.x + threadIdx.x;
  size_t stride = (size_t)gridDim.x * blockDim.x;
  for (; i < n; i += stride) x32[i] = ld_f(x, i, bf);
}

// Build concatenated weights: W1[384][256] = [Wl_f1; Wl_b1; Wr_f1+Wr_b1], b1 = bl_f1+bl_b1
//                             W2[768][256] = [Wl_f2; Wl_b2; Wr_f2+Wr_b2], b2 = bl_f2+bl_b2
__global__ void prep_params_kernel(
    const void* Wl_f1, const void* bl_f1, const void* Wr_f1,
    const void* Wl_b1, const void* bl_b1, const void* Wr_b1,
    const void* Wl_f2, const void* bl_f2, const void* Wr_f2,
    const void* Wl_b2, const void* bl_b2, const void* Wr_b2,
    const void* g1, const void* be1, const void* g2, const void* be2,
    const int* __restrict__ flags,
    float* __restrict__ W1, float* __restrict__ b1,
    float* __restrict__ W2, float* __restrict__ b2,
    float* __restrict__ gamma1, float* __restrict__ beta1,
    float* __restrict__ gamma2, float* __restrict__ beta2) {
  int bf = flags[0];
  int i = blockIdx.x * blockDim.x + threadIdx.x;
  int stride = gridDim.x * blockDim.x;
  for (int idx = i; idx < 768 * 256; idx += stride) {
    int row = idx >> 8;
    if (row < 256)      W2[idx] = ld_f(Wl_f2, idx, bf);
    else if (row < 512) W2[idx] = ld_f(Wl_b2, idx - 256 * 256, bf);
    else                W2[idx] = ld_f(Wr_f2, idx - 512 * 256, bf) + ld_f(Wr_b2, idx - 512 * 256, bf);
    if (idx < 384 * 256) {
      int r1 = idx >> 8;
      if (r1 < 128)      W1[idx] = ld_f(Wl_f1, idx, bf);
      else if (r1 < 256) W1[idx] = ld_f(Wl_b1, idx - 128 * 256, bf);
      else               W1[idx] = ld_f(Wr_f1, idx - 256 * 256, bf) + ld_f(Wr_b1, idx - 256 * 256, bf);
    }
    if (idx < 256) {
      b1[idx] = ld_f(bl_f1, idx, bf) + ld_f(bl_b1, idx, bf);
      b2[idx] = ld_f(bl_f2, idx, bf) + ld_f(bl_b2, idx, bf);
      gamma1[idx] = ld_f(g1, idx, bf);
      beta1[idx]  = ld_f(be1, idx, bf);
      gamma2[idx] = ld_f(g2, idx, bf);
      beta2[idx]  = ld_f(be2, idx, bf);
    }
  }
}

// ---------- layer 1 scatter: 32 float4-chunks per edge, both directions + degree count ----------
__global__ void scatter_l1_kernel(const float* __restrict__ x32, const int* __restrict__ src,
                                  const int* __restrict__ dst, float* __restrict__ aggf,
                                  float* __restrict__ aggb, int* __restrict__ degf,
                                  int* __restrict__ degb, int n_edges) {
  long long t = (long long)blockIdx.x * blockDim.x + threadIdx.x;
  int e = (int)(t >> 5);
  if (e >= n_edges) return;
  int c = (int)(t & 31);
  int s = src[e], d = dst[e];
  if (c == 0) { atomicAdd(&degf[d], 1); atomicAdd(&degb[s], 1); }
  const float4 xs = ((const float4*)(x32 + (size_t)s * IN_DIM))[c];
  float* pf = aggf + (size_t)d * IN_DIM + c * 4;
  atomicAdd(pf + 0, xs.x); atomicAdd(pf + 1, xs.y);
  atomicAdd(pf + 2, xs.z); atomicAdd(pf + 3, xs.w);
  const float4 xd = ((const float4*)(x32 + (size_t)d * IN_DIM))[c];
  float* pb = aggb + (size_t)s * IN_DIM + c * 4;
  atomicAdd(pb + 0, xd.x); atomicAdd(pb + 1, xd.y);
  atomicAdd(pb + 2, xd.z); atomicAdd(pb + 3, xd.w);
}

// ---------- layer 2 scatter: 64 float4-chunks per edge ----------
__global__ void scatter_l2_kernel(const float* __restrict__ h, const int* __restrict__ src,
                                  const int* __restrict__ dst, float* __restrict__ aggf,
                                  float* __restrict__ aggb, int n_edges) {
  long long t = (long long)blockIdx.x * blockDim.x + threadIdx.x;
  int e = (int)(t >> 6);
  if (e >= n_edges) return;
  int c = (int)(t & 63);
  int s = src[e], d = dst[e];
  const float4 hs = ((const float4*)(h + (size_t)s * HID))[c];
  float* pf = aggf + (size_t)d * HID + c * 4;
  atomicAdd(pf + 0, hs.x); atomicAdd(pf + 1, hs.y);
  atomicAdd(pf + 2, hs.z); atomicAdd(pf + 3, hs.w);
  const float4 hd = ((const float4*)(h + (size_t)d * HID))[c];
  float* pb = aggb + (size_t)s * HID + c * 4;
  atomicAdd(pb + 0, hd.x); atomicAdd(pb + 1, hd.y);
  atomicAdd(pb + 2, hd.z); atomicAdd(pb + 3, hd.w);
}

// ---------- GEMM: out[n, 0..255] = [aggf/deg | aggb/deg | self]·W + bias ----------
// NPB nodes per block, block = 256 threads (one output column per thread).
template <int D, int NPB>
__global__ __launch_bounds__(256) void sage_gemm_kernel(
    const float* __restrict__ aggf, const float* __restrict__ aggb,
    const float* __restrict__ self, const int* __restrict__ degf,
    const int* __restrict__ degb, const float* __restrict__ W,
    const float* __restrict__ bias, float* __restrict__ out, int n_nodes) {
  constexpr int K = 3 * D;
  __shared__ float A[NPB][K];
  const int j = threadIdx.x;
  const int n0 = blockIdx.x * NPB;
  for (int r = 0; r < NPB; ++r) {
    const int node = n0 + r;
    if (node < n_nodes) {
      const float invf = 1.0f / (float)max(degf[node], 1);
      const float invb = 1.0f / (float)max(degb[node], 1);
      for (int c = j; c < K; c += 256) {
        float v;
        if (c < D)          v = aggf[(size_t)node * D + c] * invf;
        else if (c < 2 * D) v = aggb[(size_t)node * D + (c - D)] * invb;
        else                v = self[(size_t)node * D + (c - 2 * D)];
        A[r][c] = v;
      }
    } else {
      for (int c = j; c < K; c += 256) A[r][c] = 0.0f;
    }
  }
  __syncthreads();
  float acc[NPB];
#pragma unroll
  for (int m = 0; m < NPB; ++m) acc[m] = 0.0f;
  for (int k = 0; k < K; k += 4) {
    const float w0 = W[(size_t)(k + 0) * 256 + j];
    const float w1 = W[(size_t)(k + 1) * 256 + j];
    const float w2 = W[(size_t)(k + 2) * 256 + j];
    const float w3 = W[(size_t)(k + 3) * 256 + j];
#pragma unroll
    for (int m = 0; m < NPB; ++m) {
      const float4 a = *(const float4*)&A[m][k];
      acc[m] = fmaf(a.x, w0, acc[m]);
      acc[m] = fmaf(a.y, w1, acc[m]);
      acc[m] = fmaf(a.z, w2, acc[m]);
      acc[m] = fmaf(a.w, w3, acc[m]);
    }
  }
  const float bj = bias[j];
#pragma unroll
  for (int m = 0; m < NPB; ++m) {
    const int node = n0 + m;
    if (node < n_nodes) out[(size_t)node * 256 + j] = acc[m] + bj;
  }
}

// ---------- BatchNorm stats ----------
__global__ void bn_stats_kernel(const float* __restrict__ h, int n_nodes,
                                float* __restrict__ sum, float* __restrict__ sumsq) {
  int j = threadIdx.x;
  float s = 0.f, ss = 0.f;
  for (int n = blockIdx.x; n < n_nodes; n += gridDim.x) {
    float v = h[(size_t)n * HID + j];
    s += v;
    ss = fmaf(v, v, ss);
  }
  atomicAdd(&sum[j], s);
  atomicAdd(&sumsq[j], ss);
}

__global__ void bn_finalize_kernel(const float* __restrict__ sum, const float* __restrict__ sumsq,
                                   float* __restrict__ musig, float n) {
  int j = threadIdx.x;
  float mu = sum[j] / n;
  float var = fmaxf(sumsq[j] / n - mu * mu, 0.f);
  musig[j] = mu;
  musig[j + 256] = rsqrtf(var + BN_EPS);
}

__global__ void bn_apply_kernel(float* __restrict__ h, const float* __restrict__ musig,
                                const float* __restrict__ gamma, const float* __restrict__ beta,
                                size_t total) {
  size_t idx = (size_t)blockIdx.x * 256 + threadIdx.x;
  if (idx >= total) return;
  int j = threadIdx.x;  // blockDim == 256 == row width
  float v = h[idx];
  v = gamma[j] * (v - musig[j]) * musig[j + 256] + beta[j];
  h[idx] = fmaxf(v, 0.f);
}

__global__ void bn_apply_max_kernel(const float* __restrict__ h, const float* __restrict__ musig,
                                    const float* __restrict__ gamma, const float* __restrict__ beta,
                                    int n_nodes, float* __restrict__ out_tmp) {
  int j = threadIdx.x;
  float mu = musig[j], rs = musig[j + 256], g = gamma[j], be = beta[j];
  float m = 0.f;  // ReLU output >= 0
  for (int n = blockIdx.x; n < n_nodes; n += gridDim.x) {
    float v = h[(size_t)n * HID + j];
    v = fmaxf(fmaf(g * (v - mu), rs, be), 0.f);
    m = fmaxf(m, v);
  }
  // non-negative floats compare identically as ints
  atomicMax((int*)&out_tmp[j], __float_as_int(m));
}

__global__ void write_out_kernel(const float* __restrict__ out_tmp, const int* __restrict__ flags,
                                 void* __restrict__ out, int out_size) {
  int j = threadIdx.x;
  if (j >= out_size) return;
  float v = out_tmp[j];
  if (flags[0]) ((__hip_bfloat16*)out)[j] = __float2bfloat16(v);
  else          ((float*)out)[j] = v;
}

extern "C" void kernel_launch(void* const* d_in, const int* in_sizes, int n_in,
                              void* d_out, int out_size, void* d_ws, size_t ws_size,
                              hipStream_t stream) {
  const void* x  = d_in[0];
  const void* ei = d_in[1];
  const int n_nodes = in_sizes[0] / IN_DIM;
  const int n_edges = in_sizes[1] / 2;

  // ---- workspace carve-out (float units, 4KB-aligned chunks); total ~235 MB ----
  float* ws = (float*)d_ws;
  size_t off = 0;
  auto alloc = [&](size_t n) {
    float* p = ws + off;
    off += (n + 1023) & ~(size_t)1023;
    return p;
  };
  int*   flags   = (int*)alloc(1024);
  float* W1      = alloc(384 * 256);
  float* b1      = alloc(256);
  float* W2      = alloc(768 * 256);
  float* b2      = alloc(256);
  float* gamma1  = alloc(256);
  float* beta1   = alloc(256);
  float* gamma2  = alloc(256);
  float* beta2   = alloc(256);
  float* sum1    = alloc(256);
  float* sumsq1  = alloc(256);
  float* musig1  = alloc(512);
  float* sum2    = alloc(256);
  float* sumsq2  = alloc(256);
  float* musig2  = alloc(512);
  float* out_tmp = alloc(256);
  int*   srcI    = (int*)alloc(n_edges);
  int*   dstI    = (int*)alloc(n_edges);
  int*   degf    = (int*)alloc(n_nodes);
  int*   degb    = (int*)alloc(n_nodes);
  float* x32     = alloc((size_t)n_nodes * IN_DIM);
  float* agg1    = alloc((size_t)n_nodes * 2 * IN_DIM);  // aggf1|aggb1, reused as aggf2
  float* h1      = alloc((size_t)n_nodes * HID);
  float* aggb2   = alloc((size_t)n_nodes * HID);
  float* hpre2   = alloc((size_t)n_nodes * HID);
  float* aggf1 = agg1;
  float* aggb1 = agg1 + (size_t)n_nodes * IN_DIM;
  float* aggf2 = agg1;  // 50000*256 floats, aliases layer-1 agg (dead after gemm1)
  (void)ws_size; (void)n_in;

  // ---- zero-init (d_ws is poisoned before every call) ----
  hipMemsetAsync(degf, 0, (size_t)n_nodes * 4, stream);
  hipMemsetAsync(degb, 0, (size_t)n_nodes * 4, stream);
  hipMemsetAsync(agg1, 0, (size_t)n_nodes * 2 * IN_DIM * 4, stream);
  hipMemsetAsync(aggb2, 0, (size_t)n_nodes * HID * 4, stream);
  hipMemsetAsync(sum1, 0, 256 * 4, stream);
  hipMemsetAsync(sumsq1, 0, 256 * 4, stream);
  hipMemsetAsync(sum2, 0, 256 * 4, stream);
  hipMemsetAsync(sumsq2, 0, 256 * 4, stream);
  hipMemsetAsync(out_tmp, 0, 256 * 4, stream);

  // ---- dtype detection + conversions ----
  detect_kernel<<<1, 64, 0, stream>>>((const unsigned int*)x, (const unsigned int*)ei, flags);
  convert_idx_kernel<<<(2 * n_edges + 255) / 256, 256, 0, stream>>>(ei, flags, srcI, dstI, n_edges);
  convert_x_kernel<<<2048, 256, 0, stream>>>(x, flags, x32, (size_t)n_nodes * IN_DIM);
  prep_params_kernel<<<768, 256, 0, stream>>>(
      d_in[2], d_in[3], d_in[4], d_in[5], d_in[6], d_in[7],
      d_in[8], d_in[9], d_in[10], d_in[11], d_in[12], d_in[13],
      d_in[14], d_in[15], d_in[16], d_in[17],
      flags, W1, b1, W2, b2, gamma1, beta1, gamma2, beta2);

  // ---- layer 1 ----
  {
    long long total = (long long)n_edges * 32;
    scatter_l1_kernel<<<(int)((total + 255) / 256), 256, 0, stream>>>(
        x32, srcI, dstI, aggf1, aggb1, degf, degb, n_edges);
  }
  sage_gemm_kernel<IN_DIM, 16><<<(n_nodes + 15) / 16, 256, 0, stream>>>(
      aggf1, aggb1, x32, degf, degb, W1, b1, h1, n_nodes);
  bn_stats_kernel<<<256, 256, 0, stream>>>(h1, n_nodes, sum1, sumsq1);
  bn_finalize_kernel<<<1, 256, 0, stream>>>(sum1, sumsq1, musig1, (float)n_nodes);
  bn_apply_kernel<<<n_nodes, 256, 0, stream>>>(h1, musig1, gamma1, beta1, (size_t)n_nodes * HID);

  // ---- layer 2 (aggf2 aliases agg1: re-zero after gemm1, stream-ordered) ----
  hipMemsetAsync(aggf2, 0, (size_t)n_nodes * HID * 4, stream);
  {
    long long total = (long long)n_edges * 64;
    scatter_l2_kernel<<<(int)((total + 255) / 256), 256, 0, stream>>>(
        h1, srcI, dstI, aggf2, aggb2, n_edges);
  }
  sage_gemm_kernel<HID, 16><<<(n_nodes + 15) / 16, 256, 0, stream>>>(
      aggf2, aggb2, h1, degf, degb, W2, b2, hpre2, n_nodes);
  bn_stats_kernel<<<256, 256, 0, stream>>>(hpre2, n_nodes, sum2, sumsq2);
  bn_finalize_kernel<<<1, 256, 0, stream>>>(sum2, sumsq2, musig2, (float)n_nodes);
  bn_apply_max_kernel<<<256, 256, 0, stream>>>(hpre2, musig2, gamma2, beta2, n_nodes, out_tmp);
  write_out_kernel<<<1, 256, 0, stream>>>(out_tmp, flags, d_out, out_size);
}

// Round 2
// 1240.021 us; speedup vs baseline: 4.1070x; 4.1070x over previous
//
#include <hip/hip_runtime.h>
#include <hip/hip_bf16.h>

#define IN_DIM 128
#define HID 256
#define BN_EPS 1e-5f

// ---------- dtype helpers ----------
__device__ __forceinline__ float ld_f(const void* p, size_t i, int bf16) {
  if (bf16) return __bfloat162float(((const __hip_bfloat16*)p)[i]);
  return ((const float*)p)[i];
}

// flags[0] = 1 if float arrays are bf16, 0 if f32
// flags[1] = 1 if edge_index is int32, 0 if int64
__global__ void detect_kernel(const unsigned int* __restrict__ xw,
                              const unsigned int* __restrict__ eiw,
                              int* flags) {
  if (blockIdx.x == 0 && threadIdx.x == 0) {
    int votes = 0;
    for (int i = 0; i < 256; ++i) {
      unsigned int e = (xw[i] >> 7) & 0xFFu;  // bf16 exponent field if packed bf16
      if (e >= 100u && e <= 140u) ++votes;
    }
    flags[0] = (votes > 128) ? 1 : 0;
    int nz = 0;
    for (int i = 0; i < 256; ++i)
      if (eiw[2 * i + 1] != 0u) ++nz;  // int64 node ids < 50000 -> high words all 0
    flags[1] = (nz > 0) ? 1 : 0;
  }
}

// convert indices + degree histogram (degf by dst, degb by src)
__global__ void convert_idx_kernel(const void* __restrict__ ei, const int* __restrict__ flags,
                                   int* __restrict__ src, int* __restrict__ dst,
                                   int* __restrict__ degf, int* __restrict__ degb, int n_edges) {
  int i = blockIdx.x * blockDim.x + threadIdx.x;
  if (i >= n_edges) return;
  int s, d;
  if (flags[1]) {
    s = ((const int*)ei)[i];
    d = ((const int*)ei)[n_edges + i];
  } else {
    s = (int)((const long long*)ei)[i];
    d = (int)((const long long*)ei)[n_edges + i];
  }
  src[i] = s;
  dst[i] = d;
  atomicAdd(&degf[d], 1);
  atomicAdd(&degb[s], 1);
}

__global__ void convert_x_kernel(const void* __restrict__ x, const int* __restrict__ flags,
                                 float* __restrict__ x32, size_t n) {
  int bf = flags[0];
  size_t i = (size_t)blockIdx.x * blockDim.x + threadIdx.x;
  size_t stride = (size_t)gridDim.x * blockDim.x;
  for (; i < n; i += stride) x32[i] = ld_f(x, i, bf);
}

// Build concatenated weights: W1[384][256] = [Wl_f1; Wl_b1; Wr_f1+Wr_b1], b1 = bl_f1+bl_b1
//                             W2[768][256] = [Wl_f2; Wl_b2; Wr_f2+Wr_b2], b2 = bl_f2+bl_b2
__global__ void prep_params_kernel(
    const void* Wl_f1, const void* bl_f1, const void* Wr_f1,
    const void* Wl_b1, const void* bl_b1, const void* Wr_b1,
    const void* Wl_f2, const void* bl_f2, const void* Wr_f2,
    const void* Wl_b2, const void* bl_b2, const void* Wr_b2,
    const void* g1, const void* be1, const void* g2, const void* be2,
    const int* __restrict__ flags,
    float* __restrict__ W1, float* __restrict__ b1,
    float* __restrict__ W2, float* __restrict__ b2,
    float* __restrict__ gamma1, float* __restrict__ beta1,
    float* __restrict__ gamma2, float* __restrict__ beta2) {
  int bf = flags[0];
  int i = blockIdx.x * blockDim.x + threadIdx.x;
  int stride = gridDim.x * blockDim.x;
  for (int idx = i; idx < 768 * 256; idx += stride) {
    int row = idx >> 8;
    if (row < 256)      W2[idx] = ld_f(Wl_f2, idx, bf);
    else if (row < 512) W2[idx] = ld_f(Wl_b2, idx - 256 * 256, bf);
    else                W2[idx] = ld_f(Wr_f2, idx - 512 * 256, bf) + ld_f(Wr_b2, idx - 512 * 256, bf);
    if (idx < 384 * 256) {
      int r1 = idx >> 8;
      if (r1 < 128)      W1[idx] = ld_f(Wl_f1, idx, bf);
      else if (r1 < 256) W1[idx] = ld_f(Wl_b1, idx - 128 * 256, bf);
      else               W1[idx] = ld_f(Wr_f1, idx - 256 * 256, bf) + ld_f(Wr_b1, idx - 256 * 256, bf);
    }
    if (idx < 256) {
      b1[idx] = ld_f(bl_f1, idx, bf) + ld_f(bl_b1, idx, bf);
      b2[idx] = ld_f(bl_f2, idx, bf) + ld_f(bl_b2, idx, bf);
      gamma1[idx] = ld_f(g1, idx, bf);
      beta1[idx]  = ld_f(be1, idx, bf);
      gamma2[idx] = ld_f(g2, idx, bf);
      beta2[idx]  = ld_f(be2, idx, bf);
    }
  }
}

// ---------- CSR build: block-level exclusive scan (3 kernels) ----------
// grid = 2*nb blocks; block b < nb handles degf chunk b, else degb chunk b-nb.
__global__ void scan_part_kernel(const int* __restrict__ degf, const int* __restrict__ degb,
                                 int* __restrict__ offf, int* __restrict__ offb,
                                 int* __restrict__ partials, int n, int nb) {
  __shared__ int buf[256];
  const int b = blockIdx.x;
  const int* deg = (b < nb) ? degf : degb;
  int* off = (b < nb) ? offf : offb;
  const int chunk = (b < nb) ? b : (b - nb);
  const int i = chunk * 256 + threadIdx.x;
  int v = (i < n) ? deg[i] : 0;
  buf[threadIdx.x] = v;
  __syncthreads();
  for (int s = 1; s < 256; s <<= 1) {
    int t = (threadIdx.x >= s) ? buf[threadIdx.x - s] : 0;
    __syncthreads();
    buf[threadIdx.x] += t;
    __syncthreads();
  }
  if (i < n) off[i] = buf[threadIdx.x] - v;  // local exclusive
  if (threadIdx.x == 255) partials[b] = buf[255];
}

__global__ void scan_partials_kernel(int* __restrict__ partials, int nb) {
  __shared__ int buf[256];
  for (int a = 0; a < 2; ++a) {
    int v = (threadIdx.x < nb) ? partials[a * nb + threadIdx.x] : 0;
    buf[threadIdx.x] = v;
    __syncthreads();
    for (int s = 1; s < 256; s <<= 1) {
      int t = (threadIdx.x >= s) ? buf[threadIdx.x - s] : 0;
      __syncthreads();
      buf[threadIdx.x] += t;
      __syncthreads();
    }
    if (threadIdx.x < nb) partials[a * nb + threadIdx.x] = buf[threadIdx.x] - v;
    __syncthreads();
  }
}

__global__ void scan_add_kernel(int* __restrict__ offf, int* __restrict__ offb,
                                int* __restrict__ curf, int* __restrict__ curb,
                                const int* __restrict__ partials, int n, int nb, int n_edges) {
  const int b = blockIdx.x;
  int* off = (b < nb) ? offf : offb;
  int* cur = (b < nb) ? curf : curb;
  const int chunk = (b < nb) ? b : (b - nb);
  const int i = chunk * 256 + threadIdx.x;
  if (i < n) {
    int v = off[i] + partials[b];
    off[i] = v;
    cur[i] = v;
  }
  if (b == 0 && threadIdx.x == 0) { offf[n] = n_edges; offb[n] = n_edges; }
}

__global__ void fill_adj_kernel(const int* __restrict__ src, const int* __restrict__ dst,
                                int* __restrict__ curf, int* __restrict__ curb,
                                int* __restrict__ adjf, int* __restrict__ adjb, int n_edges) {
  int i = blockIdx.x * blockDim.x + threadIdx.x;
  if (i >= n_edges) return;
  int s = src[i], d = dst[i];
  int pf = atomicAdd(&curf[d], 1);
  adjf[pf] = s;
  int pb = atomicAdd(&curb[s], 1);
  adjb[pb] = d;
}

// ---------- gather-mean aggregation: one wave per (node, direction) ----------
// D=256: lane holds float4 (64*4=256 cols). D=128: lane holds float2.
template <int D>
__global__ __launch_bounds__(256) void gather_mean_kernel(
    const float* __restrict__ feat,
    const int* __restrict__ adjf, const int* __restrict__ offf,
    const int* __restrict__ adjb, const int* __restrict__ offb,
    float* __restrict__ aggf, float* __restrict__ aggb, int n_nodes) {
  int gw = (int)((blockIdx.x * 256 + threadIdx.x) >> 6);
  int lane = threadIdx.x & 63;
  if (gw >= 2 * n_nodes) return;
  const int* adj; const int* off; float* out; int node;
  if (gw < n_nodes) { node = gw;            adj = adjf; off = offf; out = aggf; }
  else              { node = gw - n_nodes;  adj = adjb; off = offb; out = aggb; }
  const int s = off[node], e = off[node + 1];
  if (D == 256) {
    float4 acc = {0.f, 0.f, 0.f, 0.f};
    for (int i = s; i < e; ++i) {
      const float4 v = ((const float4*)(feat + (size_t)adj[i] * D))[lane];
      acc.x += v.x; acc.y += v.y; acc.z += v.z; acc.w += v.w;
    }
    const float inv = 1.0f / (float)max(e - s, 1);
    float4 r; r.x = acc.x * inv; r.y = acc.y * inv; r.z = acc.z * inv; r.w = acc.w * inv;
    ((float4*)(out + (size_t)node * D))[lane] = r;
  } else {
    float2 acc = {0.f, 0.f};
    for (int i = s; i < e; ++i) {
      const float2 v = ((const float2*)(feat + (size_t)adj[i] * D))[lane];
      acc.x += v.x; acc.y += v.y;
    }
    const float inv = 1.0f / (float)max(e - s, 1);
    float2 r; r.x = acc.x * inv; r.y = acc.y * inv;
    ((float2*)(out + (size_t)node * D))[lane] = r;
  }
}

// ---------- GEMM: out[n, 0..255] = [meanf | meanb | self]·W + bias ----------
template <int D, int NPB>
__global__ __launch_bounds__(256) void sage_gemm_kernel(
    const float* __restrict__ aggf, const float* __restrict__ aggb,
    const float* __restrict__ self, const float* __restrict__ W,
    const float* __restrict__ bias, float* __restrict__ out, int n_nodes) {
  constexpr int K = 3 * D;
  __shared__ float A[NPB][K];
  const int j = threadIdx.x;
  const int n0 = blockIdx.x * NPB;
  for (int r = 0; r < NPB; ++r) {
    const int node = n0 + r;
    if (node < n_nodes) {
      for (int c = j; c < K; c += 256) {
        float v;
        if (c < D)          v = aggf[(size_t)node * D + c];
        else if (c < 2 * D) v = aggb[(size_t)node * D + (c - D)];
        else                v = self[(size_t)node * D + (c - 2 * D)];
        A[r][c] = v;
      }
    } else {
      for (int c = j; c < K; c += 256) A[r][c] = 0.0f;
    }
  }
  __syncthreads();
  float acc[NPB];
#pragma unroll
  for (int m = 0; m < NPB; ++m) acc[m] = 0.0f;
  for (int k = 0; k < K; k += 4) {
    const float w0 = W[(size_t)(k + 0) * 256 + j];
    const float w1 = W[(size_t)(k + 1) * 256 + j];
    const float w2 = W[(size_t)(k + 2) * 256 + j];
    const float w3 = W[(size_t)(k + 3) * 256 + j];
#pragma unroll
    for (int m = 0; m < NPB; ++m) {
      const float4 a = *(const float4*)&A[m][k];
      acc[m] = fmaf(a.x, w0, acc[m]);
      acc[m] = fmaf(a.y, w1, acc[m]);
      acc[m] = fmaf(a.z, w2, acc[m]);
      acc[m] = fmaf(a.w, w3, acc[m]);
    }
  }
  const float bj = bias[j];
#pragma unroll
  for (int m = 0; m < NPB; ++m) {
    const int node = n0 + m;
    if (node < n_nodes) out[(size_t)node * 256 + j] = acc[m] + bj;
  }
}

// ---------- BatchNorm stats ----------
__global__ void bn_stats_kernel(const float* __restrict__ h, int n_nodes,
                                float* __restrict__ sum, float* __restrict__ sumsq) {
  int j = threadIdx.x;
  float s = 0.f, ss = 0.f;
  for (int n = blockIdx.x; n < n_nodes; n += gridDim.x) {
    float v = h[(size_t)n * HID + j];
    s += v;
    ss = fmaf(v, v, ss);
  }
  atomicAdd(&sum[j], s);
  atomicAdd(&sumsq[j], ss);
}

__global__ void bn_finalize_kernel(const float* __restrict__ sum, const float* __restrict__ sumsq,
                                   float* __restrict__ musig, float n) {
  int j = threadIdx.x;
  float mu = sum[j] / n;
  float var = fmaxf(sumsq[j] / n - mu * mu, 0.f);
  musig[j] = mu;
  musig[j + 256] = rsqrtf(var + BN_EPS);
}

__global__ void bn_apply_kernel(float* __restrict__ h, const float* __restrict__ musig,
                                const float* __restrict__ gamma, const float* __restrict__ beta,
                                size_t total) {
  size_t idx = (size_t)blockIdx.x * 256 + threadIdx.x;
  if (idx >= total) return;
  int j = threadIdx.x;  // blockDim == 256 == row width
  float v = h[idx];
  v = gamma[j] * (v - musig[j]) * musig[j + 256] + beta[j];
  h[idx] = fmaxf(v, 0.f);
}

__global__ void bn_apply_max_kernel(const float* __restrict__ h, const float* __restrict__ musig,
                                    const float* __restrict__ gamma, const float* __restrict__ beta,
                                    int n_nodes, float* __restrict__ out_tmp) {
  int j = threadIdx.x;
  float mu = musig[j], rs = musig[j + 256], g = gamma[j], be = beta[j];
  float m = 0.f;  // ReLU output >= 0
  for (int n = blockIdx.x; n < n_nodes; n += gridDim.x) {
    float v = h[(size_t)n * HID + j];
    v = fmaxf(fmaf(g * (v - mu), rs, be), 0.f);
    m = fmaxf(m, v);
  }
  atomicMax((int*)&out_tmp[j], __float_as_int(m));
}

__global__ void write_out_kernel(const float* __restrict__ out_tmp, const int* __restrict__ flags,
                                 void* __restrict__ out, int out_size) {
  int j = threadIdx.x;
  if (j >= out_size) return;
  float v = out_tmp[j];
  if (flags[0]) ((__hip_bfloat16*)out)[j] = __float2bfloat16(v);
  else          ((float*)out)[j] = v;
}

extern "C" void kernel_launch(void* const* d_in, const int* in_sizes, int n_in,
                              void* d_out, int out_size, void* d_ws, size_t ws_size,
                              hipStream_t stream) {
  const void* x  = d_in[0];
  const void* ei = d_in[1];
  const int n_nodes = in_sizes[0] / IN_DIM;
  const int n_edges = in_sizes[1] / 2;
  const int nb = (n_nodes + 255) / 256;  // scan chunks per array

  // ---- workspace carve-out (float units, 4KB-aligned chunks) ----
  float* ws = (float*)d_ws;
  size_t off = 0;
  auto alloc = [&](size_t n) {
    float* p = ws + off;
    off += (n + 1023) & ~(size_t)1023;
    return p;
  };
  int*   flags   = (int*)alloc(1024);
  float* W1      = alloc(384 * 256);
  float* b1      = alloc(256);
  float* W2      = alloc(768 * 256);
  float* b2      = alloc(256);
  float* gamma1  = alloc(256);
  float* beta1   = alloc(256);
  float* gamma2  = alloc(256);
  float* beta2   = alloc(256);
  float* sum1    = alloc(256);
  float* sumsq1  = alloc(256);
  float* musig1  = alloc(512);
  float* sum2    = alloc(256);
  float* sumsq2  = alloc(256);
  float* musig2  = alloc(512);
  float* out_tmp = alloc(256);
  int*   srcI    = (int*)alloc(n_edges);
  int*   dstI    = (int*)alloc(n_edges);
  int*   degf    = (int*)alloc(n_nodes);
  int*   degb    = (int*)alloc(n_nodes);
  int*   offf    = (int*)alloc(n_nodes + 1);
  int*   offb    = (int*)alloc(n_nodes + 1);
  int*   curf    = (int*)alloc(n_nodes);
  int*   curb    = (int*)alloc(n_nodes);
  int*   adjf    = (int*)alloc(n_edges);
  int*   adjb    = (int*)alloc(n_edges);
  int*   partials = (int*)alloc(2 * nb);
  float* x32     = alloc((size_t)n_nodes * IN_DIM);
  float* agg1    = alloc((size_t)n_nodes * 2 * IN_DIM);  // aggf1|aggb1, reused as aggf2
  float* h1      = alloc((size_t)n_nodes * HID);
  float* aggb2   = alloc((size_t)n_nodes * HID);
  float* hpre2   = alloc((size_t)n_nodes * HID);
  float* aggf1 = agg1;
  float* aggb1 = agg1 + (size_t)n_nodes * IN_DIM;
  float* aggf2 = agg1;  // aliases layer-1 agg (dead after gemm1)
  (void)ws_size; (void)n_in;

  // ---- zero-init (d_ws is poisoned before every call) ----
  hipMemsetAsync(degf, 0, (size_t)n_nodes * 4, stream);
  hipMemsetAsync(degb, 0, (size_t)n_nodes * 4, stream);
  hipMemsetAsync(sum1, 0, 256 * 4, stream);
  hipMemsetAsync(sumsq1, 0, 256 * 4, stream);
  hipMemsetAsync(sum2, 0, 256 * 4, stream);
  hipMemsetAsync(sumsq2, 0, 256 * 4, stream);
  hipMemsetAsync(out_tmp, 0, 256 * 4, stream);

  // ---- dtype detection + conversions + histogram ----
  detect_kernel<<<1, 64, 0, stream>>>((const unsigned int*)x, (const unsigned int*)ei, flags);
  convert_idx_kernel<<<(n_edges + 255) / 256, 256, 0, stream>>>(ei, flags, srcI, dstI, degf, degb, n_edges);
  convert_x_kernel<<<2048, 256, 0, stream>>>(x, flags, x32, (size_t)n_nodes * IN_DIM);
  prep_params_kernel<<<768, 256, 0, stream>>>(
      d_in[2], d_in[3], d_in[4], d_in[5], d_in[6], d_in[7],
      d_in[8], d_in[9], d_in[10], d_in[11], d_in[12], d_in[13],
      d_in[14], d_in[15], d_in[16], d_in[17],
      flags, W1, b1, W2, b2, gamma1, beta1, gamma2, beta2);

  // ---- CSR build ----
  scan_part_kernel<<<2 * nb, 256, 0, stream>>>(degf, degb, offf, offb, partials, n_nodes, nb);
  scan_partials_kernel<<<1, 256, 0, stream>>>(partials, nb);
  scan_add_kernel<<<2 * nb, 256, 0, stream>>>(offf, offb, curf, curb, partials, n_nodes, nb, n_edges);
  fill_adj_kernel<<<(n_edges + 255) / 256, 256, 0, stream>>>(srcI, dstI, curf, curb, adjf, adjb, n_edges);

  // ---- layer 1: gather-mean + GEMM + BN/ReLU ----
  {
    int waves = 2 * n_nodes;
    gather_mean_kernel<IN_DIM><<<(waves + 3) / 4, 256, 0, stream>>>(
        x32, adjf, offf, adjb, offb, aggf1, aggb1, n_nodes);
  }
  sage_gemm_kernel<IN_DIM, 16><<<(n_nodes + 15) / 16, 256, 0, stream>>>(
      aggf1, aggb1, x32, W1, b1, h1, n_nodes);
  bn_stats_kernel<<<256, 256, 0, stream>>>(h1, n_nodes, sum1, sumsq1);
  bn_finalize_kernel<<<1, 256, 0, stream>>>(sum1, sumsq1, musig1, (float)n_nodes);
  bn_apply_kernel<<<n_nodes, 256, 0, stream>>>(h1, musig1, gamma1, beta1, (size_t)n_nodes * HID);

  // ---- layer 2 (aggf2 aliases agg1, stream-ordered reuse) ----
  {
    int waves = 2 * n_nodes;
    gather_mean_kernel<HID><<<(waves + 3) / 4, 256, 0, stream>>>(
        h1, adjf, offf, adjb, offb, aggf2, aggb2, n_nodes);
  }
  sage_gemm_kernel<HID, 16><<<(n_nodes + 15) / 16, 256, 0, stream>>>(
      aggf2, aggb2, h1, W2, b2, hpre2, n_nodes);
  bn_stats_kernel<<<256, 256, 0, stream>>>(hpre2, n_nodes, sum2, sumsq2);
  bn_finalize_kernel<<<1, 256, 0, stream>>>(sum2, sumsq2, musig2, (float)n_nodes);
  bn_apply_max_kernel<<<256, 256, 0, stream>>>(hpre2, musig2, gamma2, beta2, n_nodes, out_tmp);
  write_out_kernel<<<1, 256, 0, stream>>>(out_tmp, flags, d_out, out_size);
}

// Round 3
// 552.221 us; speedup vs baseline: 9.2223x; 2.2455x over previous
//
#include <hip/hip_runtime.h>
#include <hip/hip_bf16.h>

#define IN_DIM 128
#define HID 256
#define BN_EPS 1e-5f

typedef __attribute__((ext_vector_type(8))) short bf16x8;
typedef __attribute__((ext_vector_type(16))) float f32x16;

// ---------- dtype helpers ----------
__device__ __forceinline__ float ld_f(const void* p, size_t i, int bf16) {
  if (bf16) return __bfloat162float(((const __hip_bfloat16*)p)[i]);
  return ((const float*)p)[i];
}
__device__ __forceinline__ float blo(unsigned u) { return __uint_as_float(u << 16); }
__device__ __forceinline__ float bhi(unsigned u) { return __uint_as_float(u & 0xffff0000u); }
__device__ __forceinline__ unsigned short f2bf(float f) {
  __hip_bfloat16 b = __float2bfloat16(f);
  return __builtin_bit_cast(unsigned short, b);
}

// flags[0] = 1 if float arrays are bf16, 0 if f32
// flags[1] = 1 if edge_index is int32, 0 if int64
__global__ void detect_kernel(const unsigned int* __restrict__ xw,
                              const unsigned int* __restrict__ eiw, int* flags) {
  if (blockIdx.x == 0 && threadIdx.x == 0) {
    int votes = 0;
    for (int i = 0; i < 256; ++i) {
      unsigned int e = (xw[i] >> 7) & 0xFFu;
      if (e >= 100u && e <= 140u) ++votes;
    }
    flags[0] = (votes > 128) ? 1 : 0;
    int nz = 0;
    for (int i = 0; i < 256; ++i)
      if (eiw[2 * i + 1] != 0u) ++nz;
    flags[1] = (nz > 0) ? 1 : 0;
  }
}

// convert indices + degree histogram (degf by dst, degb by src)
__global__ void convert_idx_kernel(const void* __restrict__ ei, const int* __restrict__ flags,
                                   int* __restrict__ src, int* __restrict__ dst,
                                   int* __restrict__ degf, int* __restrict__ degb, int n_edges) {
  int i = blockIdx.x * blockDim.x + threadIdx.x;
  if (i >= n_edges) return;
  int s, d;
  if (flags[1]) {
    s = ((const int*)ei)[i];
    d = ((const int*)ei)[n_edges + i];
  } else {
    s = (int)((const long long*)ei)[i];
    d = (int)((const long long*)ei)[n_edges + i];
  }
  src[i] = s;
  dst[i] = d;
  atomicAdd(&degf[d], 1);
  atomicAdd(&degb[s], 1);
}

// x -> bf16 self-slice of A1 (cols 256..383 of row-stride-384 matrix)
__global__ void convert_x_kernel(const void* __restrict__ x, const int* __restrict__ flags,
                                 __hip_bfloat16* __restrict__ A1, int n_nodes) {
  int bf = flags[0];
  size_t idx = (size_t)blockIdx.x * blockDim.x + threadIdx.x;
  size_t n = (size_t)n_nodes * IN_DIM;
  if (idx >= n) return;
  int row = (int)(idx >> 7), j = (int)(idx & 127);
  float v = ld_f(x, idx, bf);
  A1[(size_t)row * 384 + 256 + j] = __float2bfloat16(v);
}

// Pack weights into MFMA B-fragment order + fold biases.
// Wpk layout: element index ((t*STEPS + s)*64 + l)*8 + j  <->  W[k=s*16+(l>>5)*8+j][col=t*32+(l&31)]
__global__ void prep_params_kernel(
    const void* Wl_f1, const void* bl_f1, const void* Wr_f1,
    const void* Wl_b1, const void* bl_b1, const void* Wr_b1,
    const void* Wl_f2, const void* bl_f2, const void* Wr_f2,
    const void* Wl_b2, const void* bl_b2, const void* Wr_b2,
    const void* g1, const void* be1, const void* g2, const void* be2,
    const int* __restrict__ flags,
    __hip_bfloat16* __restrict__ Wpk1, float* __restrict__ b1,
    __hip_bfloat16* __restrict__ Wpk2, float* __restrict__ b2,
    float* __restrict__ gamma1, float* __restrict__ beta1,
    float* __restrict__ gamma2, float* __restrict__ beta2) {
  int bf = flags[0];
  int idx = blockIdx.x * blockDim.x + threadIdx.x;
  if (idx >= 768 * 256) return;
  {  // layer 2 pack (STEPS=48)
    int j = idx & 7, l = (idx >> 3) & 63, rest = idx >> 9;
    int s = rest % 48, t = rest / 48;
    int k = s * 16 + (l >> 5) * 8 + j, col = t * 32 + (l & 31);
    float v;
    if (k < 256)      v = ld_f(Wl_f2, (size_t)k * 256 + col, bf);
    else if (k < 512) v = ld_f(Wl_b2, (size_t)(k - 256) * 256 + col, bf);
    else              v = ld_f(Wr_f2, (size_t)(k - 512) * 256 + col, bf) +
                          ld_f(Wr_b2, (size_t)(k - 512) * 256 + col, bf);
    Wpk2[idx] = __float2bfloat16(v);
  }
  if (idx < 384 * 256) {  // layer 1 pack (STEPS=24)
    int j = idx & 7, l = (idx >> 3) & 63, rest = idx >> 9;
    int s = rest % 24, t = rest / 24;
    int k = s * 16 + (l >> 5) * 8 + j, col = t * 32 + (l & 31);
    float v;
    if (k < 128)      v = ld_f(Wl_f1, (size_t)k * 256 + col, bf);
    else if (k < 256) v = ld_f(Wl_b1, (size_t)(k - 128) * 256 + col, bf);
    else              v = ld_f(Wr_f1, (size_t)(k - 256) * 256 + col, bf) +
                          ld_f(Wr_b1, (size_t)(k - 256) * 256 + col, bf);
    Wpk1[idx] = __float2bfloat16(v);
  }
  if (idx < 256) {
    b1[idx] = ld_f(bl_f1, idx, bf) + ld_f(bl_b1, idx, bf);
    b2[idx] = ld_f(bl_f2, idx, bf) + ld_f(bl_b2, idx, bf);
    gamma1[idx] = ld_f(g1, idx, bf);
    beta1[idx]  = ld_f(be1, idx, bf);
    gamma2[idx] = ld_f(g2, idx, bf);
    beta2[idx]  = ld_f(be2, idx, bf);
  }
}

// ---------- CSR build ----------
__global__ void scan_part_kernel(const int* __restrict__ degf, const int* __restrict__ degb,
                                 int* __restrict__ offf, int* __restrict__ offb,
                                 int* __restrict__ partials, int n, int nb) {
  __shared__ int buf[256];
  const int b = blockIdx.x;
  const int* deg = (b < nb) ? degf : degb;
  int* off = (b < nb) ? offf : offb;
  const int chunk = (b < nb) ? b : (b - nb);
  const int i = chunk * 256 + threadIdx.x;
  int v = (i < n) ? deg[i] : 0;
  buf[threadIdx.x] = v;
  __syncthreads();
  for (int s = 1; s < 256; s <<= 1) {
    int t = (threadIdx.x >= s) ? buf[threadIdx.x - s] : 0;
    __syncthreads();
    buf[threadIdx.x] += t;
    __syncthreads();
  }
  if (i < n) off[i] = buf[threadIdx.x] - v;
  if (threadIdx.x == 255) partials[b] = buf[255];
}

__global__ void scan_partials_kernel(int* __restrict__ partials, int nb) {
  __shared__ int buf[256];
  for (int a = 0; a < 2; ++a) {
    int v = (threadIdx.x < nb) ? partials[a * nb + threadIdx.x] : 0;
    buf[threadIdx.x] = v;
    __syncthreads();
    for (int s = 1; s < 256; s <<= 1) {
      int t = (threadIdx.x >= s) ? buf[threadIdx.x - s] : 0;
      __syncthreads();
      buf[threadIdx.x] += t;
      __syncthreads();
    }
    if (threadIdx.x < nb) partials[a * nb + threadIdx.x] = buf[threadIdx.x] - v;
    __syncthreads();
  }
}

__global__ void scan_add_kernel(int* __restrict__ offf, int* __restrict__ offb,
                                int* __restrict__ curf, int* __restrict__ curb,
                                const int* __restrict__ partials, int n, int nb, int n_edges) {
  const int b = blockIdx.x;
  int* off = (b < nb) ? offf : offb;
  int* cur = (b < nb) ? curf : curb;
  const int chunk = (b < nb) ? b : (b - nb);
  const int i = chunk * 256 + threadIdx.x;
  if (i < n) {
    int v = off[i] + partials[b];
    off[i] = v;
    cur[i] = v;
  }
  if (b == 0 && threadIdx.x == 0) { offf[n] = n_edges; offb[n] = n_edges; }
}

__global__ void fill_adj_kernel(const int* __restrict__ src, const int* __restrict__ dst,
                                int* __restrict__ curf, int* __restrict__ curb,
                                int* __restrict__ adjf, int* __restrict__ adjb, int n_edges) {
  int i = blockIdx.x * blockDim.x + threadIdx.x;
  if (i >= n_edges) return;
  int s = src[i], d = dst[i];
  adjf[atomicAdd(&curf[d], 1)] = s;
  adjb[atomicAdd(&curb[s], 1)] = d;
}

// ---------- gather-mean (bf16 in, bf16 out), multi-neighbor per wave ----------
// A: row stride 3D; self-slice at col 2D (source); writes mean at col 0 (fwd) / D (bwd).
template <int D>
__global__ __launch_bounds__(256) void gather_mean_kernel(
    __hip_bfloat16* __restrict__ A,
    const int* __restrict__ adjf, const int* __restrict__ offf,
    const int* __restrict__ adjb, const int* __restrict__ offb, int n_nodes) {
  constexpr int LPN = D / 8;     // lanes per neighbor row (16B = 8 bf16 each)
  constexpr int NPI = 64 / LPN;  // neighbors per iteration
  const int gw = (int)(((size_t)blockIdx.x * 256 + threadIdx.x) >> 6);
  const int lane = threadIdx.x & 63;
  if (gw >= 2 * n_nodes) return;
  int node, dir;
  const int *adj, *off;
  if (gw < n_nodes) { node = gw;           adj = adjf; off = offf; dir = 0; }
  else              { node = gw - n_nodes; adj = adjb; off = offb; dir = 1; }
  const int s = off[node], e = off[node + 1];
  const int sub = lane / LPN, cl = lane % LPN;
  float acc[8] = {0.f, 0.f, 0.f, 0.f, 0.f, 0.f, 0.f, 0.f};
  for (int i = s; i < e; i += NPI) {
    const int idx = i + sub;
    if (idx < e) {
      const int nb = adj[idx];
      const uint4 w = *(const uint4*)(A + (size_t)nb * (3 * D) + 2 * D + cl * 8);
      acc[0] += blo(w.x); acc[1] += bhi(w.x);
      acc[2] += blo(w.y); acc[3] += bhi(w.y);
      acc[4] += blo(w.z); acc[5] += bhi(w.z);
      acc[6] += blo(w.w); acc[7] += bhi(w.w);
    }
  }
#pragma unroll
  for (int o = 32; o >= LPN; o >>= 1) {
#pragma unroll
    for (int k = 0; k < 8; ++k) acc[k] += __shfl_xor(acc[k], o, 64);
  }
  if (sub == 0) {
    const float inv = 1.0f / (float)max(e - s, 1);
    union { unsigned short us[8]; uint4 v; } o;
#pragma unroll
    for (int k = 0; k < 8; ++k) o.us[k] = f2bf(acc[k] * inv);
    *(uint4*)(A + (size_t)node * (3 * D) + dir * D + cl * 8) = o.v;
  }
}

// ---------- MFMA GEMM: C[M][256] = A[M][K]*Wpk + bias, fused BN sum/sumsq ----------
// block = 4 waves: wave (rg,cg) computes rows [blk*64+rg*32, +32) x cols [cg*128, +128)
template <int K>
__global__ __launch_bounds__(256, 2) void gemm_mfma_kernel(
    const __hip_bfloat16* __restrict__ A, const __hip_bfloat16* __restrict__ Wpk,
    const float* __restrict__ bias, float* __restrict__ C,
    float* __restrict__ bnsum, float* __restrict__ bnsum2, int M) {
  constexpr int STEPS = K / 16;
  __shared__ float colsum[256], colsum2[256];
  colsum[threadIdx.x] = 0.f;
  colsum2[threadIdx.x] = 0.f;
  __syncthreads();
  const int wave = threadIdx.x >> 6, lane = threadIdx.x & 63;
  const int rg = wave & 1, cg = wave >> 1;
  const int rbase = blockIdx.x * 64 + rg * 32;
  const int cbase = cg * 128;
  const __hip_bfloat16* aptr = A + (size_t)(rbase + (lane & 31)) * K + (lane >> 5) * 8;
  const __hip_bfloat16* wptr = Wpk + (size_t)(cg * 4) * STEPS * 512 + lane * 8;
  f32x16 acc0 = {}, acc1 = {}, acc2 = {}, acc3 = {};
  for (int s = 0; s < STEPS; ++s) {
    bf16x8 af = *(const bf16x8*)aptr;
    aptr += 16;
    bf16x8 w0 = *(const bf16x8*)(wptr);
    bf16x8 w1 = *(const bf16x8*)(wptr + (size_t)1 * STEPS * 512);
    bf16x8 w2 = *(const bf16x8*)(wptr + (size_t)2 * STEPS * 512);
    bf16x8 w3 = *(const bf16x8*)(wptr + (size_t)3 * STEPS * 512);
    wptr += 512;
    acc0 = __builtin_amdgcn_mfma_f32_32x32x16_bf16(af, w0, acc0, 0, 0, 0);
    acc1 = __builtin_amdgcn_mfma_f32_32x32x16_bf16(af, w1, acc1, 0, 0, 0);
    acc2 = __builtin_amdgcn_mfma_f32_32x32x16_bf16(af, w2, acc2, 0, 0, 0);
    acc3 = __builtin_amdgcn_mfma_f32_32x32x16_bf16(af, w3, acc3, 0, 0, 0);
  }
  f32x16 accs[4] = {acc0, acc1, acc2, acc3};
#pragma unroll
  for (int t = 0; t < 4; ++t) {
    const int col = cbase + t * 32 + (lane & 31);
    const float bj = bias[col];
    float ls = 0.f, ls2 = 0.f;
#pragma unroll
    for (int r = 0; r < 16; ++r) {
      const int row = rbase + (r & 3) + 8 * (r >> 2) + 4 * (lane >> 5);
      if (row < M) {
        float v = accs[t][r] + bj;
        C[(size_t)row * 256 + col] = v;
        ls += v;
        ls2 = fmaf(v, v, ls2);
      }
    }
    atomicAdd(&colsum[col], ls);
    atomicAdd(&colsum2[col], ls2);
  }
  __syncthreads();
  atomicAdd(&bnsum[threadIdx.x], colsum[threadIdx.x]);
  atomicAdd(&bnsum2[threadIdx.x], colsum2[threadIdx.x]);
}

// ---------- BN ----------
__global__ void bn_finalize_kernel(const float* __restrict__ sum, const float* __restrict__ sumsq,
                                   float* __restrict__ musig, float n) {
  int j = threadIdx.x;
  float mu = sum[j] / n;
  float var = fmaxf(sumsq[j] / n - mu * mu, 0.f);
  musig[j] = mu;
  musig[j + 256] = rsqrtf(var + BN_EPS);
}

// BN+ReLU h1 -> bf16 self-slice of A2 (cols 512..767, row stride 768); one block per row
__global__ void bn_apply_bf16_kernel(const float* __restrict__ hpre, const float* __restrict__ musig,
                                     const float* __restrict__ gamma, const float* __restrict__ beta,
                                     __hip_bfloat16* __restrict__ A2) {
  int j = threadIdx.x;
  int row = blockIdx.x;
  float v = hpre[(size_t)row * 256 + j];
  v = fmaxf(fmaf(gamma[j] * (v - musig[j]), musig[j + 256], beta[j]), 0.f);
  A2[(size_t)row * 768 + 512 + j] = __float2bfloat16(v);
}

__global__ void bn_apply_max_kernel(const float* __restrict__ h, const float* __restrict__ musig,
                                    const float* __restrict__ gamma, const float* __restrict__ beta,
                                    int n_nodes, float* __restrict__ out_tmp) {
  int j = threadIdx.x;
  float mu = musig[j], rs = musig[j + 256], g = gamma[j], be = beta[j];
  float m = 0.f;  // ReLU output >= 0
  for (int n = blockIdx.x; n < n_nodes; n += gridDim.x) {
    float v = h[(size_t)n * HID + j];
    v = fmaxf(fmaf(g * (v - mu), rs, be), 0.f);
    m = fmaxf(m, v);
  }
  atomicMax((int*)&out_tmp[j], __float_as_int(m));
}

__global__ void write_out_kernel(const float* __restrict__ out_tmp, const int* __restrict__ flags,
                                 void* __restrict__ out, int out_size) {
  int j = threadIdx.x;
  if (j >= out_size) return;
  float v = out_tmp[j];
  if (flags[0]) ((__hip_bfloat16*)out)[j] = __float2bfloat16(v);
  else          ((float*)out)[j] = v;
}

extern "C" void kernel_launch(void* const* d_in, const int* in_sizes, int n_in,
                              void* d_out, int out_size, void* d_ws, size_t ws_size,
                              hipStream_t stream) {
  const void* x  = d_in[0];
  const void* ei = d_in[1];
  const int n_nodes = in_sizes[0] / IN_DIM;
  const int n_edges = in_sizes[1] / 2;
  const int nb = (n_nodes + 255) / 256;
  const int Mpad = (n_nodes + 63) & ~63;

  float* ws = (float*)d_ws;
  size_t off = 0;
  auto alloc = [&](size_t n) {
    float* p = ws + off;
    off += (n + 1023) & ~(size_t)1023;
    return p;
  };
  int*   flags   = (int*)alloc(1024);
  __hip_bfloat16* Wpk1 = (__hip_bfloat16*)alloc(384 * 256 / 2);
  __hip_bfloat16* Wpk2 = (__hip_bfloat16*)alloc(768 * 256 / 2);
  float* b1      = alloc(256);
  float* b2      = alloc(256);
  float* gamma1  = alloc(256);
  float* beta1   = alloc(256);
  float* gamma2  = alloc(256);
  float* beta2   = alloc(256);
  float* sum1    = alloc(256);
  float* sumsq1  = alloc(256);
  float* musig1  = alloc(512);
  float* sum2    = alloc(256);
  float* sumsq2  = alloc(256);
  float* musig2  = alloc(512);
  float* out_tmp = alloc(256);
  int*   srcI    = (int*)alloc(n_edges);
  int*   dstI    = (int*)alloc(n_edges);
  int*   degf    = (int*)alloc(n_nodes);
  int*   degb    = (int*)alloc(n_nodes);
  int*   offf    = (int*)alloc(n_nodes + 1);
  int*   offb    = (int*)alloc(n_nodes + 1);
  int*   curf    = (int*)alloc(n_nodes);
  int*   curb    = (int*)alloc(n_nodes);
  int*   adjf    = (int*)alloc(n_edges);
  int*   adjb    = (int*)alloc(n_edges);
  int*   partials = (int*)alloc(2 * nb);
  __hip_bfloat16* A1 = (__hip_bfloat16*)alloc((size_t)Mpad * 384 / 2);
  __hip_bfloat16* A2 = (__hip_bfloat16*)alloc((size_t)Mpad * 768 / 2);
  float* hpre    = alloc((size_t)n_nodes * HID);  // shared by layer 1 & 2
  (void)ws_size; (void)n_in;

  hipMemsetAsync(degf, 0, (size_t)n_nodes * 4, stream);
  hipMemsetAsync(degb, 0, (size_t)n_nodes * 4, stream);
  hipMemsetAsync(sum1, 0, 256 * 4, stream);
  hipMemsetAsync(sumsq1, 0, 256 * 4, stream);
  hipMemsetAsync(sum2, 0, 256 * 4, stream);
  hipMemsetAsync(sumsq2, 0, 256 * 4, stream);
  hipMemsetAsync(out_tmp, 0, 256 * 4, stream);

  detect_kernel<<<1, 64, 0, stream>>>((const unsigned int*)x, (const unsigned int*)ei, flags);
  convert_idx_kernel<<<(n_edges + 255) / 256, 256, 0, stream>>>(ei, flags, srcI, dstI, degf, degb, n_edges);
  convert_x_kernel<<<(n_nodes * IN_DIM + 255) / 256, 256, 0, stream>>>(x, flags, A1, n_nodes);
  prep_params_kernel<<<768, 256, 0, stream>>>(
      d_in[2], d_in[3], d_in[4], d_in[5], d_in[6], d_in[7],
      d_in[8], d_in[9], d_in[10], d_in[11], d_in[12], d_in[13],
      d_in[14], d_in[15], d_in[16], d_in[17],
      flags, Wpk1, b1, Wpk2, b2, gamma1, beta1, gamma2, beta2);

  scan_part_kernel<<<2 * nb, 256, 0, stream>>>(degf, degb, offf, offb, partials, n_nodes, nb);
  scan_partials_kernel<<<1, 256, 0, stream>>>(partials, nb);
  scan_add_kernel<<<2 * nb, 256, 0, stream>>>(offf, offb, curf, curb, partials, n_nodes, nb, n_edges);
  fill_adj_kernel<<<(n_edges + 255) / 256, 256, 0, stream>>>(srcI, dstI, curf, curb, adjf, adjb, n_edges);

  // ---- layer 1 ----
  gather_mean_kernel<IN_DIM><<<(2 * n_nodes + 3) / 4, 256, 0, stream>>>(
      A1, adjf, offf, adjb, offb, n_nodes);
  gemm_mfma_kernel<384><<<Mpad / 64, 256, 0, stream>>>(
      A1, Wpk1, b1, hpre, sum1, sumsq1, n_nodes);
  bn_finalize_kernel<<<1, 256, 0, stream>>>(sum1, sumsq1, musig1, (float)n_nodes);
  bn_apply_bf16_kernel<<<n_nodes, 256, 0, stream>>>(hpre, musig1, gamma1, beta1, A2);

  // ---- layer 2 ----
  gather_mean_kernel<HID><<<(2 * n_nodes + 3) / 4, 256, 0, stream>>>(
      A2, adjf, offf, adjb, offb, n_nodes);
  gemm_mfma_kernel<768><<<Mpad / 64, 256, 0, stream>>>(
      A2, Wpk2, b2, hpre, sum2, sumsq2, n_nodes);
  bn_finalize_kernel<<<1, 256, 0, stream>>>(sum2, sumsq2, musig2, (float)n_nodes);
  bn_apply_max_kernel<<<1024, 256, 0, stream>>>(hpre, musig2, gamma2, beta2, n_nodes, out_tmp);
  write_out_kernel<<<1, 256, 0, stream>>>(out_tmp, flags, d_out, out_size);
}